// Round 9
// baseline (133.489 us; speedup 1.0000x reference)
//
#include <hip/hip_runtime.h>
#include <hip/hip_bf16.h>
#include <math.h>

#define N 8192
#define D 128
#define MARGIN 0.3f

#define NSTRIP 64            // 128-row strips
#define BPS 8                // blocks per strip
#define TPB 9                // 64-col j-tiles per block: 72-offset window
#define GRID_MAIN (NSTRIP * BPS)   // 512 uniform blocks = full residency @2/CU

typedef float f32x4 __attribute__((ext_vector_type(4)));
typedef short bf16x8 __attribute__((ext_vector_type(8)));
typedef unsigned short u16x8 __attribute__((ext_vector_type(8)));

__device__ inline unsigned short f2bf(float f) {
    unsigned u = __float_as_uint(f);
    unsigned r = (u + 0x7FFFu + ((u >> 16) & 1u)) >> 16;
    return (unsigned short)r;
}

// ---------- convert fp32 -> bf16 + row norms + init mining arrays ----------
__global__ __launch_bounds__(256) void convert_kernel(const float* __restrict__ X,
                                                      unsigned short* __restrict__ Xb,
                                                      float* __restrict__ sq,
                                                      unsigned* __restrict__ ap2,
                                                      unsigned* __restrict__ an2) {
    int tid = threadIdx.x;
    int row = blockIdx.x * 16 + (tid >> 4);
    int l = tid & 15;
    const float4* p = reinterpret_cast<const float4*>(X + (size_t)row * D + l * 8);
    float4 u = p[0];
    float4 v = p[1];
    float s = u.x*u.x + u.y*u.y + u.z*u.z + u.w*u.w
            + v.x*v.x + v.y*v.y + v.z*v.z + v.w*v.w;
    u16x8 o;
    o[0] = f2bf(u.x); o[1] = f2bf(u.y); o[2] = f2bf(u.z); o[3] = f2bf(u.w);
    o[4] = f2bf(v.x); o[5] = f2bf(v.y); o[6] = f2bf(v.z); o[7] = f2bf(v.w);
    *reinterpret_cast<u16x8*>(Xb + (size_t)row * D + l * 8) = o;
    #pragma unroll
    for (int off = 8; off >= 1; off >>= 1) s += __shfl_xor(s, off);
    if (l == 0) {
        sq[row] = s;
        ap2[row] = 0u;            // 0.0f  (< any clipped d2)
        an2[row] = 0x7F7F7F7Fu;   // huge  (> any d2)
    }
}

// ---------- main: barrier-free symmetric Gram, register-pipelined ----------
// Strip bi (128 rows) x 64-col j-tiles jj=(2bi+o)&127, o in [0,72):
// covers every unordered macro-pair (d in [0,32] needed; d in (32,36) are
// harmless duplicates computed from both sides). jmine only o in [2,64):
// o in {0,1} diagonal square (i-mining self-covers), o in [64,72) transpose
// is computed by the partner strip with jmine on (or i-mined both sides, d=32).
// No LDS, no barriers. A-frags (strip-constant) fully register-cached; B-frags
// + meta double-buffered in registers: next tile's loads issue at tile top and
// land during this tile's MFMA+epilogue (~550 cyc vs ~200 cyc L2 latency).
__global__ __launch_bounds__(256, 2) void triplet_main(
        const unsigned short* __restrict__ Xb,
        const int* __restrict__ lbl,
        const float* __restrict__ sq,
        unsigned* __restrict__ ap2,
        unsigned* __restrict__ an2) {
    const int bi = blockIdx.x >> 3;
    const int s  = blockIdx.x & 7;
    const int base = s * TPB;
    const int jwin0 = 2 * bi;

    const int tid = threadIdx.x;
    const int w = tid >> 6;        // wave 0..3
    const int lane = tid & 63;
    const int wr = w >> 1;         // wave-tile: 64 rows x 32 cols of 128x64 C
    const int wc = w & 1;
    const int quad = lane >> 4;
    const int lx = lane & 15;
    const int i0 = bi * 128;

    int lbl_i[16];
    float sqi_r[16];
    #pragma unroll
    for (int tr = 0; tr < 4; ++tr)
        #pragma unroll
        for (int v = 0; v < 4; ++v) {
            int row = i0 + wr * 64 + tr * 16 + quad * 4 + v;
            lbl_i[tr * 4 + v] = lbl[row];
            sqi_r[tr * 4 + v] = sq[row];
        }

    float m_ap[16], m_an[16];
    #pragma unroll
    for (int q = 0; q < 16; ++q) { m_ap[q] = -INFINITY; m_an[q] = INFINITY; }

    // A fragments: strip-constant, cache all 4 ks x 4 tr (64 VGPR)
    bf16x8 afc[4][4];
    #pragma unroll
    for (int ks = 0; ks < 4; ++ks)
        #pragma unroll
        for (int tr = 0; tr < 4; ++tr) {
            int rA = i0 + wr * 64 + tr * 16 + lx;
            afc[ks][tr] = *reinterpret_cast<const bf16x8*>(
                Xb + (size_t)rA * D + ks * 32 + quad * 8);
        }

    // B double buffer (registers) + meta double buffer
    bf16x8 bA[8], bB[8];
    float mA[2], mB[2];
    int   lA[2], lB[2];
    {
        int jj0 = (jwin0 + base) & 127;
        #pragma unroll
        for (int tc = 0; tc < 2; ++tc) {
            int jc = jj0 * 64 + wc * 32 + tc * 16 + lx;
            #pragma unroll
            for (int ks = 0; ks < 4; ++ks)
                bA[ks * 2 + tc] = *reinterpret_cast<const bf16x8*>(
                    Xb + (size_t)jc * D + ks * 32 + quad * 8);
            mA[tc] = sq[jc];
            lA[tc] = lbl[jc];
        }
    }

    #pragma unroll
    for (int t = 0; t < TPB; ++t) {
        bf16x8 (&bc)[8] = (t & 1) ? bB : bA;
        bf16x8 (&bn)[8] = (t & 1) ? bA : bB;
        float (&mc)[2] = (t & 1) ? mB : mA;
        float (&mn)[2] = (t & 1) ? mA : mB;
        int (&lc)[2] = (t & 1) ? lB : lA;
        int (&ln)[2] = (t & 1) ? lA : lB;

        const int o = base + t;
        const int jj = (jwin0 + o) & 127;

        // prefetch next tile's B fragments + meta into the alternate buffer
        if (t + 1 < TPB) {
            int jjn = (jwin0 + o + 1) & 127;
            #pragma unroll
            for (int tc = 0; tc < 2; ++tc) {
                int jcn = jjn * 64 + wc * 32 + tc * 16 + lx;
                #pragma unroll
                for (int ks = 0; ks < 4; ++ks)
                    bn[ks * 2 + tc] = *reinterpret_cast<const bf16x8*>(
                        Xb + (size_t)jcn * D + ks * 32 + quad * 8);
                mn[tc] = sq[jcn];
                ln[tc] = lbl[jcn];
            }
        }

        f32x4 acc[4][2];
        #pragma unroll
        for (int a = 0; a < 4; ++a)
            #pragma unroll
            for (int c = 0; c < 2; ++c)
                acc[a][c] = (f32x4){0.f, 0.f, 0.f, 0.f};

        #pragma unroll
        for (int ks = 0; ks < 4; ++ks)
            #pragma unroll
            for (int tr = 0; tr < 4; ++tr)
                #pragma unroll
                for (int tc = 0; tc < 2; ++tc)
                    acc[tr][tc] = __builtin_amdgcn_mfma_f32_16x16x32_bf16(
                        afc[ks][tr], bc[ks * 2 + tc], acc[tr][tc], 0, 0, 0);

        // ---- epilogue: dual-direction masked mining ----
        const bool jmine = (o >= 2) & (o < 64);
        #pragma unroll
        for (int tc = 0; tc < 2; ++tc) {
            float mApJ = -INFINITY, mAnJ = INFINITY;
            #pragma unroll
            for (int tr = 0; tr < 4; ++tr) {
                #pragma unroll
                for (int v = 0; v < 4; ++v) {
                    int q = tr * 4 + v;
                    float a = acc[tr][tc][v];
                    float vi = fmaf(-2.f, a, mc[tc]);    // mine for row i
                    float vj = fmaf(-2.f, a, sqi_r[q]);  // mine for col j
                    bool same = (lc[tc] == lbl_i[q]);
                    m_ap[q] = same ? fmaxf(m_ap[q], vi) : m_ap[q];
                    m_an[q] = same ? m_an[q] : fminf(m_an[q], vi);
                    mApJ = same ? fmaxf(mApJ, vj) : mApJ;
                    mAnJ = same ? mAnJ : fminf(mAnJ, vj);
                }
            }
            if (jmine) {
                #pragma unroll
                for (int off = 16; off <= 32; off <<= 1) {
                    mApJ = fmaxf(mApJ, __shfl_xor(mApJ, off));
                    mAnJ = fminf(mAnJ, __shfl_xor(mAnJ, off));
                }
                if (quad == 0) {
                    int jc = jj * 64 + wc * 32 + tc * 16 + lx;
                    float vap = fmaxf(mc[tc] + mApJ, 1e-12f);
                    float van = fmaxf(mc[tc] + mAnJ, 1e-12f);
                    atomicMax(&ap2[jc], __float_as_uint(vap));
                    atomicMin(&an2[jc], __float_as_uint(van));
                }
            }
        }
    }

    // i-direction: reduce over the 16 j-lanes, one atomic pair per row per wave
    #pragma unroll
    for (int off = 8; off >= 1; off >>= 1) {
        #pragma unroll
        for (int q = 0; q < 16; ++q) {
            m_ap[q] = fmaxf(m_ap[q], __shfl_xor(m_ap[q], off));
            m_an[q] = fminf(m_an[q], __shfl_xor(m_an[q], off));
        }
    }
    if (lx == 0) {
        #pragma unroll
        for (int tr = 0; tr < 4; ++tr) {
            #pragma unroll
            for (int v = 0; v < 4; ++v) {
                int q = tr * 4 + v;
                int row = i0 + wr * 64 + tr * 16 + quad * 4 + v;
                float vap = fmaxf(sqi_r[q] + m_ap[q], 1e-12f);
                float van = fmaxf(sqi_r[q] + m_an[q], 1e-12f);
                atomicMax(&ap2[row], __float_as_uint(vap));
                atomicMin(&an2[row], __float_as_uint(van));
            }
        }
    }
}

// ---------- finalize: sqrt + hinge + mean ----------
__global__ __launch_bounds__(1024) void finalize_kernel(const unsigned* __restrict__ ap2,
                                                        const unsigned* __restrict__ an2,
                                                        float* __restrict__ out) {
    int tid = threadIdx.x;
    float ls = 0.f, ps = 0.f;
    for (int row = tid; row < N; row += 1024) {
        float ap = sqrtf(__uint_as_float(ap2[row]));
        float an = sqrtf(__uint_as_float(an2[row]));
        ls += fmaxf(0.f, MARGIN - (an - ap));
        ps += (an > ap) ? 1.f : 0.f;
    }
    #pragma unroll
    for (int off = 32; off >= 1; off >>= 1) {
        ls += __shfl_xor(ls, off);
        ps += __shfl_xor(ps, off);
    }
    __shared__ float red[2][16];
    int w = tid >> 6;
    if ((tid & 63) == 0) { red[0][w] = ls; red[1][w] = ps; }
    __syncthreads();
    if (tid == 0) {
        float L = 0.f, P = 0.f;
        #pragma unroll
        for (int i = 0; i < 16; ++i) { L += red[0][i]; P += red[1][i]; }
        out[0] = L / (float)N;
        out[1] = P / (float)N;
    }
}

extern "C" void kernel_launch(void* const* d_in, const int* in_sizes, int n_in,
                              void* d_out, int out_size, void* d_ws, size_t ws_size,
                              hipStream_t stream) {
    const float* X = (const float*)d_in[0];
    const int* lbl = (const int*)d_in[1];
    float* out = (float*)d_out;

    float* sq = (float*)d_ws;                               // N floats
    unsigned* ap2 = (unsigned*)d_ws + N;                    // N uints
    unsigned* an2 = (unsigned*)d_ws + 2 * N;                // N uints
    unsigned short* Xb = (unsigned short*)((char*)d_ws + 3 * N * sizeof(unsigned)); // N*D bf16

    convert_kernel<<<N / 16, 256, 0, stream>>>(X, Xb, sq, ap2, an2);
    triplet_main<<<GRID_MAIN, 256, 0, stream>>>(Xb, lbl, sq, ap2, an2);
    finalize_kernel<<<1, 1024, 0, stream>>>(ap2, an2, out);
}

// Round 10
// 101.044 us; speedup vs baseline: 1.3211x; 1.3211x over previous
//
#include <hip/hip_runtime.h>
#include <hip/hip_bf16.h>
#include <math.h>

#define N 8192
#define D 128
#define MARGIN 0.3f

#define NSTRIP 64            // 128-row strips
#define BPS 11               // blocks per strip
#define TPB 6                // 64-col j-tiles per block (11*6 = 66 offsets)
#define GRID_MAIN (NSTRIP * BPS)   // 704

typedef float f32x4 __attribute__((ext_vector_type(4)));
typedef short bf16x8 __attribute__((ext_vector_type(8)));
typedef unsigned short u16x8 __attribute__((ext_vector_type(8)));

#define AS1 __attribute__((address_space(1)))
#define AS3 __attribute__((address_space(3)))

__device__ inline void gload_lds16(const void* g, void* l) {
    __builtin_amdgcn_global_load_lds((AS1 void*)(void*)(g), (AS3 void*)(l), 16, 0, 0);
}

__device__ inline unsigned short f2bf(float f) {
    unsigned u = __float_as_uint(f);
    unsigned r = (u + 0x7FFFu + ((u >> 16) & 1u)) >> 16;
    return (unsigned short)r;
}

// ---------- convert fp32 -> bf16 + row norms + init mining arrays ----------
__global__ __launch_bounds__(256) void convert_kernel(const float* __restrict__ X,
                                                      unsigned short* __restrict__ Xb,
                                                      float* __restrict__ sq,
                                                      unsigned* __restrict__ ap2,
                                                      unsigned* __restrict__ an2) {
    int tid = threadIdx.x;
    int row = blockIdx.x * 16 + (tid >> 4);
    int l = tid & 15;
    const float4* p = reinterpret_cast<const float4*>(X + (size_t)row * D + l * 8);
    float4 u = p[0];
    float4 v = p[1];
    float s = u.x*u.x + u.y*u.y + u.z*u.z + u.w*u.w
            + v.x*v.x + v.y*v.y + v.z*v.z + v.w*v.w;
    u16x8 o;
    o[0] = f2bf(u.x); o[1] = f2bf(u.y); o[2] = f2bf(u.z); o[3] = f2bf(u.w);
    o[4] = f2bf(v.x); o[5] = f2bf(v.y); o[6] = f2bf(v.z); o[7] = f2bf(v.w);
    *reinterpret_cast<u16x8*>(Xb + (size_t)row * D + l * 8) = o;
    #pragma unroll
    for (int off = 8; off >= 1; off >>= 1) s += __shfl_xor(s, off);
    if (l == 0) {
        sq[row] = s;
        ap2[row] = 0u;            // 0.0f  (< any clipped d2)
        an2[row] = 0x7F7F7F7Fu;   // huge  (> any d2)
    }
}

// ---------- main: r7 structure + half-A register cache ----------
// Strip bi (128 rows) covers 64-col j-tiles jj=(2bi+o)&127, o in [0,66): every
// unordered macro-pair once (o in {0,1}: diagonal self-square; o in {64,65}:
// transpose covered by the partner strip -> jmine only for o in [2,64)).
// 11 blocks/strip x 6 offsets = uniform 704-block grid; 48 KB LDS -> 3 blocks/CU.
// Per tile: MFMA -> barrier -> restage Bs (dead during epilogue) -> dual-mining
// epilogue (hides restage flight) -> barrier. afc[2][4] caches ks=0,1 A-frags
// in registers (32 VGPR, statically indexed -> no spill; cuts per-tile
// ds_read_b128 from 24 to 16).
// LDS row-major, 16B chunks; LDS chunk c of row r holds global chunk c^(r&7).
__global__ __launch_bounds__(256, 3) void triplet_main(
        const unsigned short* __restrict__ Xb,
        const int* __restrict__ lbl,
        const float* __restrict__ sq,
        unsigned* __restrict__ ap2,
        unsigned* __restrict__ an2) {
    __shared__ unsigned short As[128 * D];   // 32 KB, resident whole block
    __shared__ unsigned short Bs[64 * D];    // 16 KB, restaged per tile

    const int bi = blockIdx.x / BPS;
    const int s  = blockIdx.x - bi * BPS;
    const int base = s * TPB;
    const int jwin0 = 2 * bi;

    const int tid = threadIdx.x;
    const int w = tid >> 6;        // wave 0..3
    const int lane = tid & 63;
    const int wr = w >> 1;         // wave-tile: 64 rows x 32 cols of 128x64 C
    const int wc = w & 1;
    const int quad = lane >> 4;
    const int lx = lane & 15;
    const int i0 = bi * 128;

    int lbl_i[16];
    float sqi_r[16];
    #pragma unroll
    for (int tr = 0; tr < 4; ++tr)
        #pragma unroll
        for (int v = 0; v < 4; ++v) {
            int row = i0 + wr * 64 + tr * 16 + quad * 4 + v;
            lbl_i[tr * 4 + v] = lbl[row];
            sqi_r[tr * 4 + v] = sq[row];
        }

    float m_ap[16], m_an[16];
    #pragma unroll
    for (int q = 0; q < 16; ++q) { m_ap[q] = -INFINITY; m_an[q] = INFINITY; }

    // stage A strip (128 rows x 16 chunks)
    #pragma unroll
    for (int t = 0; t < 8; ++t) {
        int rbase = w * 32 + t * 4;
        int r = rbase + quad;
        int gc = lx ^ (r & 7);
        gload_lds16(Xb + (size_t)(i0 + r) * D + gc * 8, &As[rbase * D]);
    }
    // stage B tile 0 (64 rows x 16 chunks)
    {
        int jj0 = (jwin0 + base) & 127;
        #pragma unroll
        for (int t = 0; t < 4; ++t) {
            int rbase = w * 16 + t * 4;
            int r = rbase + quad;
            int gc = lx ^ (r & 7);
            gload_lds16(Xb + (size_t)(jj0 * 64 + r) * D + gc * 8, &Bs[rbase * D]);
        }
    }
    __syncthreads();   // staging drained

    // cache A fragments for ks = 0,1 (block-constant; As is never overwritten)
    bf16x8 afc[2][4];
    #pragma unroll
    for (int ks = 0; ks < 2; ++ks)
        #pragma unroll
        for (int tr = 0; tr < 4; ++tr) {
            int rA = wr * 64 + tr * 16 + lx;
            int sc = (ks * 4 + quad) ^ (lx & 7);
            afc[ks][tr] = *reinterpret_cast<const bf16x8*>(&As[rA * D + sc * 8]);
        }

    #pragma unroll 1
    for (int t = 0; t < TPB; ++t) {
        const int o = base + t;
        const int jj = (jwin0 + o) & 127;

        // per-lane j metadata (L2-hit loads; drained by the post-MFMA barrier)
        float sqj[2]; int lblj[2];
        #pragma unroll
        for (int tc = 0; tc < 2; ++tc) {
            int jc = jj * 64 + wc * 32 + tc * 16 + lx;
            sqj[tc] = sq[jc];
            lblj[tc] = lbl[jc];
        }

        f32x4 acc[4][2];
        #pragma unroll
        for (int a = 0; a < 4; ++a)
            #pragma unroll
            for (int c = 0; c < 2; ++c)
                acc[a][c] = (f32x4){0.f, 0.f, 0.f, 0.f};

        #pragma unroll
        for (int ks = 0; ks < 4; ++ks) {
            bf16x8 af[4], bf[2];
            if (ks < 2) {
                #pragma unroll
                for (int tr = 0; tr < 4; ++tr) af[tr] = afc[ks][tr];
            } else {
                #pragma unroll
                for (int tr = 0; tr < 4; ++tr) {
                    int rA = wr * 64 + tr * 16 + lx;
                    int sc = (ks * 4 + quad) ^ (lx & 7);
                    af[tr] = *reinterpret_cast<const bf16x8*>(&As[rA * D + sc * 8]);
                }
            }
            #pragma unroll
            for (int tc = 0; tc < 2; ++tc) {
                int rB = wc * 32 + tc * 16 + lx;
                int sc = (ks * 4 + quad) ^ (lx & 7);
                bf[tc] = *reinterpret_cast<const bf16x8*>(&Bs[rB * D + sc * 8]);
            }
            #pragma unroll
            for (int tr = 0; tr < 4; ++tr)
                #pragma unroll
                for (int tc = 0; tc < 2; ++tc)
                    acc[tr][tc] = __builtin_amdgcn_mfma_f32_16x16x32_bf16(
                        af[tr], bf[tc], acc[tr][tc], 0, 0, 0);
        }

        __syncthreads();   // all waves done reading Bs -> safe to overwrite

        // restage Bs with the next tile; flight hidden by the epilogue below
        if (t + 1 < TPB) {
            int jjn = (jwin0 + o + 1) & 127;
            #pragma unroll
            for (int tt = 0; tt < 4; ++tt) {
                int rbase = w * 16 + tt * 4;
                int r = rbase + quad;
                int gc = lx ^ (r & 7);
                gload_lds16(Xb + (size_t)(jjn * 64 + r) * D + gc * 8, &Bs[rbase * D]);
            }
        }

        // ---- epilogue: dual-direction masked mining on -2*dot ----
        const bool jmine = (o >= 2) & (o < 64);
        #pragma unroll
        for (int tc = 0; tc < 2; ++tc) {
            float mApJ = -INFINITY, mAnJ = INFINITY;
            #pragma unroll
            for (int tr = 0; tr < 4; ++tr) {
                #pragma unroll
                for (int v = 0; v < 4; ++v) {
                    int q = tr * 4 + v;
                    float a = acc[tr][tc][v];
                    float vi = fmaf(-2.f, a, sqj[tc]);   // mine for row i
                    float vj = fmaf(-2.f, a, sqi_r[q]);  // mine for col j
                    bool same = (lblj[tc] == lbl_i[q]);
                    m_ap[q] = same ? fmaxf(m_ap[q], vi) : m_ap[q];
                    m_an[q] = same ? m_an[q] : fminf(m_an[q], vi);
                    mApJ = same ? fmaxf(mApJ, vj) : mApJ;
                    mAnJ = same ? mAnJ : fminf(mAnJ, vj);
                }
            }
            if (jmine) {
                #pragma unroll
                for (int off = 16; off <= 32; off <<= 1) {
                    mApJ = fmaxf(mApJ, __shfl_xor(mApJ, off));
                    mAnJ = fminf(mAnJ, __shfl_xor(mAnJ, off));
                }
                if (quad == 0) {
                    int jc = jj * 64 + wc * 32 + tc * 16 + lx;
                    float vap = fmaxf(sqj[tc] + mApJ, 1e-12f);
                    float van = fmaxf(sqj[tc] + mAnJ, 1e-12f);
                    atomicMax(&ap2[jc], __float_as_uint(vap));
                    atomicMin(&an2[jc], __float_as_uint(van));
                }
            }
        }

        if (t + 1 < TPB) __syncthreads();   // restage drained -> Bs = next tile
    }

    // i-direction: reduce over the 16 j-lanes, one atomic pair per row per wave
    #pragma unroll
    for (int off = 8; off >= 1; off >>= 1) {
        #pragma unroll
        for (int q = 0; q < 16; ++q) {
            m_ap[q] = fmaxf(m_ap[q], __shfl_xor(m_ap[q], off));
            m_an[q] = fminf(m_an[q], __shfl_xor(m_an[q], off));
        }
    }
    if (lx == 0) {
        #pragma unroll
        for (int tr = 0; tr < 4; ++tr) {
            #pragma unroll
            for (int v = 0; v < 4; ++v) {
                int q = tr * 4 + v;
                int row = i0 + wr * 64 + tr * 16 + quad * 4 + v;
                float vap = fmaxf(sqi_r[q] + m_ap[q], 1e-12f);
                float van = fmaxf(sqi_r[q] + m_an[q], 1e-12f);
                atomicMax(&ap2[row], __float_as_uint(vap));
                atomicMin(&an2[row], __float_as_uint(van));
            }
        }
    }
}

// ---------- finalize: sqrt + hinge + mean ----------
__global__ __launch_bounds__(1024) void finalize_kernel(const unsigned* __restrict__ ap2,
                                                        const unsigned* __restrict__ an2,
                                                        float* __restrict__ out) {
    int tid = threadIdx.x;
    float ls = 0.f, ps = 0.f;
    for (int row = tid; row < N; row += 1024) {
        float ap = sqrtf(__uint_as_float(ap2[row]));
        float an = sqrtf(__uint_as_float(an2[row]));
        ls += fmaxf(0.f, MARGIN - (an - ap));
        ps += (an > ap) ? 1.f : 0.f;
    }
    #pragma unroll
    for (int off = 32; off >= 1; off >>= 1) {
        ls += __shfl_xor(ls, off);
        ps += __shfl_xor(ps, off);
    }
    __shared__ float red[2][16];
    int w = tid >> 6;
    if ((tid & 63) == 0) { red[0][w] = ls; red[1][w] = ps; }
    __syncthreads();
    if (tid == 0) {
        float L = 0.f, P = 0.f;
        #pragma unroll
        for (int i = 0; i < 16; ++i) { L += red[0][i]; P += red[1][i]; }
        out[0] = L / (float)N;
        out[1] = P / (float)N;
    }
}

extern "C" void kernel_launch(void* const* d_in, const int* in_sizes, int n_in,
                              void* d_out, int out_size, void* d_ws, size_t ws_size,
                              hipStream_t stream) {
    const float* X = (const float*)d_in[0];
    const int* lbl = (const int*)d_in[1];
    float* out = (float*)d_out;

    float* sq = (float*)d_ws;                               // N floats
    unsigned* ap2 = (unsigned*)d_ws + N;                    // N uints
    unsigned* an2 = (unsigned*)d_ws + 2 * N;                // N uints
    unsigned short* Xb = (unsigned short*)((char*)d_ws + 3 * N * sizeof(unsigned)); // N*D bf16

    convert_kernel<<<N / 16, 256, 0, stream>>>(X, Xb, sq, ap2, an2);
    triplet_main<<<GRID_MAIN, 256, 0, stream>>>(Xb, lbl, sq, ap2, an2);
    finalize_kernel<<<1, 1024, 0, stream>>>(ap2, an2, out);
}

// Round 11
// 97.755 us; speedup vs baseline: 1.3655x; 1.0336x over previous
//
#include <hip/hip_runtime.h>
#include <hip/hip_bf16.h>
#include <math.h>

#define N 8192
#define D 128
#define MARGIN 0.3f

#define NSTRIP 128           // 64-row strips
#define BPS 13               // blocks per strip
#define TPB 5                // 64-col j-tiles per block (13*5 = 65 offsets)
#define GRID_MAIN (NSTRIP * BPS)   // 1664

typedef float f32x4 __attribute__((ext_vector_type(4)));
typedef short bf16x8 __attribute__((ext_vector_type(8)));
typedef unsigned short u16x8 __attribute__((ext_vector_type(8)));

#define AS1 __attribute__((address_space(1)))
#define AS3 __attribute__((address_space(3)))

__device__ inline void gload_lds16(const void* g, void* l) {
    __builtin_amdgcn_global_load_lds((AS1 void*)(void*)(g), (AS3 void*)(l), 16, 0, 0);
}

__device__ inline unsigned short f2bf(float f) {
    unsigned u = __float_as_uint(f);
    unsigned r = (u + 0x7FFFu + ((u >> 16) & 1u)) >> 16;
    return (unsigned short)r;
}

// ---------- convert fp32 -> bf16 + row norms + init mining arrays ----------
__global__ __launch_bounds__(256) void convert_kernel(const float* __restrict__ X,
                                                      unsigned short* __restrict__ Xb,
                                                      float* __restrict__ sq,
                                                      unsigned* __restrict__ ap2,
                                                      unsigned* __restrict__ an2) {
    int tid = threadIdx.x;
    int row = blockIdx.x * 16 + (tid >> 4);
    int l = tid & 15;
    const float4* p = reinterpret_cast<const float4*>(X + (size_t)row * D + l * 8);
    float4 u = p[0];
    float4 v = p[1];
    float s = u.x*u.x + u.y*u.y + u.z*u.z + u.w*u.w
            + v.x*v.x + v.y*v.y + v.z*v.z + v.w*v.w;
    u16x8 o;
    o[0] = f2bf(u.x); o[1] = f2bf(u.y); o[2] = f2bf(u.z); o[3] = f2bf(u.w);
    o[4] = f2bf(v.x); o[5] = f2bf(v.y); o[6] = f2bf(v.z); o[7] = f2bf(v.w);
    *reinterpret_cast<u16x8*>(Xb + (size_t)row * D + l * 8) = o;
    #pragma unroll
    for (int off = 8; off >= 1; off >>= 1) s += __shfl_xor(s, off);
    if (l == 0) {
        sq[row] = s;
        ap2[row] = 0u;            // 0.0f  (< any clipped d2)
        an2[row] = 0x7F7F7F7Fu;   // huge  (> any d2)
    }
}

// ---------- main: 64-row strips, 32 KB LDS -> 4 blocks/CU (16 waves) ----------
// Strip si (64 rows) covers 64-col tiles jj=(si+o)&127, o in [0,65): pair
// distance d in [0,64]. d in [1,64): computed once by the lower strip with
// j-mining; d=64: computed by BOTH strips i-dir only; d=0: self tile, i-dir
// covers both orders. jmine for o in [1,64). 13 blocks/strip x 5 offsets.
// 4 waves in 2x2 over the 64x64 C-tile (wave-tile 32x32). A-frags fully
// register-cached (afc[4][2], 32 VGPR static). Per tile: MFMA -> barrier ->
// restage Bs (dead during epilogue) -> dual-mining epilogue -> barrier.
// LDS row-major, 16B chunks; LDS chunk c of row r holds global chunk c^(r&7).
__global__ __launch_bounds__(256, 4) void triplet_main(
        const unsigned short* __restrict__ Xb,
        const int* __restrict__ lbl,
        const float* __restrict__ sq,
        unsigned* __restrict__ ap2,
        unsigned* __restrict__ an2) {
    __shared__ unsigned short As[64 * D];   // 16 KB, resident whole block
    __shared__ unsigned short Bs[64 * D];   // 16 KB, restaged per tile

    const int si = blockIdx.x / BPS;
    const int s  = blockIdx.x - si * BPS;
    const int base = s * TPB;

    const int tid = threadIdx.x;
    const int w = tid >> 6;        // wave 0..3
    const int lane = tid & 63;
    const int wr = w >> 1;         // wave-tile: 32 rows x 32 cols of 64x64 C
    const int wc = w & 1;
    const int quad = lane >> 4;
    const int lx = lane & 15;
    const int i0 = si * 64;

    int lbl_i[8];
    float sqi_r[8];
    #pragma unroll
    for (int tr = 0; tr < 2; ++tr)
        #pragma unroll
        for (int v = 0; v < 4; ++v) {
            int row = i0 + wr * 32 + tr * 16 + quad * 4 + v;
            lbl_i[tr * 4 + v] = lbl[row];
            sqi_r[tr * 4 + v] = sq[row];
        }

    float m_ap[8], m_an[8];
    #pragma unroll
    for (int q = 0; q < 8; ++q) { m_ap[q] = -INFINITY; m_an[q] = INFINITY; }

    // stage A strip (64 rows x 16 chunks) and B tile 0
    #pragma unroll
    for (int t = 0; t < 4; ++t) {
        int rbase = w * 16 + t * 4;
        int r = rbase + quad;
        int gc = lx ^ (r & 7);
        gload_lds16(Xb + (size_t)(i0 + r) * D + gc * 8, &As[rbase * D]);
    }
    {
        int jj0 = (si + base) & 127;
        #pragma unroll
        for (int t = 0; t < 4; ++t) {
            int rbase = w * 16 + t * 4;
            int r = rbase + quad;
            int gc = lx ^ (r & 7);
            gload_lds16(Xb + (size_t)(jj0 * 64 + r) * D + gc * 8, &Bs[rbase * D]);
        }
    }
    __syncthreads();   // staging drained

    // A fragments -> registers (block-constant; As never overwritten)
    bf16x8 afc[4][2];
    #pragma unroll
    for (int ks = 0; ks < 4; ++ks)
        #pragma unroll
        for (int tr = 0; tr < 2; ++tr) {
            int rA = wr * 32 + tr * 16 + lx;
            int sc = (ks * 4 + quad) ^ (lx & 7);
            afc[ks][tr] = *reinterpret_cast<const bf16x8*>(&As[rA * D + sc * 8]);
        }

    #pragma unroll 1
    for (int t = 0; t < TPB; ++t) {
        const int o = base + t;
        const int jj = (si + o) & 127;

        // per-lane j metadata (L2-hit loads; drained by the post-MFMA barrier)
        float sqj[2]; int lblj[2];
        #pragma unroll
        for (int tc = 0; tc < 2; ++tc) {
            int jc = jj * 64 + wc * 32 + tc * 16 + lx;
            sqj[tc] = sq[jc];
            lblj[tc] = lbl[jc];
        }

        f32x4 acc[2][2];
        #pragma unroll
        for (int a = 0; a < 2; ++a)
            #pragma unroll
            for (int c = 0; c < 2; ++c)
                acc[a][c] = (f32x4){0.f, 0.f, 0.f, 0.f};

        #pragma unroll
        for (int ks = 0; ks < 4; ++ks) {
            bf16x8 bf[2];
            #pragma unroll
            for (int tc = 0; tc < 2; ++tc) {
                int rB = wc * 32 + tc * 16 + lx;
                int sc = (ks * 4 + quad) ^ (lx & 7);
                bf[tc] = *reinterpret_cast<const bf16x8*>(&Bs[rB * D + sc * 8]);
            }
            #pragma unroll
            for (int tr = 0; tr < 2; ++tr)
                #pragma unroll
                for (int tc = 0; tc < 2; ++tc)
                    acc[tr][tc] = __builtin_amdgcn_mfma_f32_16x16x32_bf16(
                        afc[ks][tr], bf[tc], acc[tr][tc], 0, 0, 0);
        }

        __syncthreads();   // all waves done reading Bs -> safe to overwrite

        // restage Bs with the next tile; flight hidden by the epilogue below
        if (t + 1 < TPB) {
            int jjn = (si + o + 1) & 127;
            #pragma unroll
            for (int tt = 0; tt < 4; ++tt) {
                int rbase = w * 16 + tt * 4;
                int r = rbase + quad;
                int gc = lx ^ (r & 7);
                gload_lds16(Xb + (size_t)(jjn * 64 + r) * D + gc * 8, &Bs[rbase * D]);
            }
        }

        // ---- epilogue: dual-direction masked mining on -2*dot ----
        const bool jmine = (o >= 1) & (o < 64);
        #pragma unroll
        for (int tc = 0; tc < 2; ++tc) {
            float mApJ = -INFINITY, mAnJ = INFINITY;
            #pragma unroll
            for (int tr = 0; tr < 2; ++tr) {
                #pragma unroll
                for (int v = 0; v < 4; ++v) {
                    int q = tr * 4 + v;
                    float a = acc[tr][tc][v];
                    float vi = fmaf(-2.f, a, sqj[tc]);   // mine for row i
                    float vj = fmaf(-2.f, a, sqi_r[q]);  // mine for col j
                    bool same = (lblj[tc] == lbl_i[q]);
                    m_ap[q] = same ? fmaxf(m_ap[q], vi) : m_ap[q];
                    m_an[q] = same ? m_an[q] : fminf(m_an[q], vi);
                    mApJ = same ? fmaxf(mApJ, vj) : mApJ;
                    mAnJ = same ? mAnJ : fminf(mAnJ, vj);
                }
            }
            if (jmine) {
                #pragma unroll
                for (int off = 16; off <= 32; off <<= 1) {
                    mApJ = fmaxf(mApJ, __shfl_xor(mApJ, off));
                    mAnJ = fminf(mAnJ, __shfl_xor(mAnJ, off));
                }
                if (quad == 0) {
                    int jc = jj * 64 + wc * 32 + tc * 16 + lx;
                    float vap = fmaxf(sqj[tc] + mApJ, 1e-12f);
                    float van = fmaxf(sqj[tc] + mAnJ, 1e-12f);
                    atomicMax(&ap2[jc], __float_as_uint(vap));
                    atomicMin(&an2[jc], __float_as_uint(van));
                }
            }
        }

        if (t + 1 < TPB) __syncthreads();   // restage drained -> Bs = next tile
    }

    // i-direction: reduce over the 16 j-lanes, one atomic pair per row per wave
    #pragma unroll
    for (int off = 8; off >= 1; off >>= 1) {
        #pragma unroll
        for (int q = 0; q < 8; ++q) {
            m_ap[q] = fmaxf(m_ap[q], __shfl_xor(m_ap[q], off));
            m_an[q] = fminf(m_an[q], __shfl_xor(m_an[q], off));
        }
    }
    if (lx == 0) {
        #pragma unroll
        for (int tr = 0; tr < 2; ++tr) {
            #pragma unroll
            for (int v = 0; v < 4; ++v) {
                int q = tr * 4 + v;
                int row = i0 + wr * 32 + tr * 16 + quad * 4 + v;
                float vap = fmaxf(sqi_r[q] + m_ap[q], 1e-12f);
                float van = fmaxf(sqi_r[q] + m_an[q], 1e-12f);
                atomicMax(&ap2[row], __float_as_uint(vap));
                atomicMin(&an2[row], __float_as_uint(van));
            }
        }
    }
}

// ---------- finalize: sqrt + hinge + mean ----------
__global__ __launch_bounds__(1024) void finalize_kernel(const unsigned* __restrict__ ap2,
                                                        const unsigned* __restrict__ an2,
                                                        float* __restrict__ out) {
    int tid = threadIdx.x;
    float ls = 0.f, ps = 0.f;
    for (int row = tid; row < N; row += 1024) {
        float ap = sqrtf(__uint_as_float(ap2[row]));
        float an = sqrtf(__uint_as_float(an2[row]));
        ls += fmaxf(0.f, MARGIN - (an - ap));
        ps += (an > ap) ? 1.f : 0.f;
    }
    #pragma unroll
    for (int off = 32; off >= 1; off >>= 1) {
        ls += __shfl_xor(ls, off);
        ps += __shfl_xor(ps, off);
    }
    __shared__ float red[2][16];
    int w = tid >> 6;
    if ((tid & 63) == 0) { red[0][w] = ls; red[1][w] = ps; }
    __syncthreads();
    if (tid == 0) {
        float L = 0.f, P = 0.f;
        #pragma unroll
        for (int i = 0; i < 16; ++i) { L += red[0][i]; P += red[1][i]; }
        out[0] = L / (float)N;
        out[1] = P / (float)N;
    }
}

extern "C" void kernel_launch(void* const* d_in, const int* in_sizes, int n_in,
                              void* d_out, int out_size, void* d_ws, size_t ws_size,
                              hipStream_t stream) {
    const float* X = (const float*)d_in[0];
    const int* lbl = (const int*)d_in[1];
    float* out = (float*)d_out;

    float* sq = (float*)d_ws;                               // N floats
    unsigned* ap2 = (unsigned*)d_ws + N;                    // N uints
    unsigned* an2 = (unsigned*)d_ws + 2 * N;                // N uints
    unsigned short* Xb = (unsigned short*)((char*)d_ws + 3 * N * sizeof(unsigned)); // N*D bf16

    convert_kernel<<<N / 16, 256, 0, stream>>>(X, Xb, sq, ap2, an2);
    triplet_main<<<GRID_MAIN, 256, 0, stream>>>(Xb, lbl, sq, ap2, an2);
    finalize_kernel<<<1, 1024, 0, stream>>>(ap2, an2, out);
}